// Round 13
// baseline (331.257 us; speedup 1.0000x reference)
//
#include <hip/hip_runtime.h>

typedef unsigned int uint;
typedef unsigned short ushort;
typedef __attribute__((ext_vector_type(8))) short bf16x8;
typedef __attribute__((ext_vector_type(4))) float f32x4;

__device__ inline ushort f2bf(float f) {           // f32 -> bf16 RNE
    uint u = __float_as_uint(f);
    u += 0x7fff + ((u >> 16) & 1);
    return (ushort)(u >> 16);
}
__device__ inline uint pkbf(float lo, float hi) {  // 2xf32 -> packed bf16 pair (RNE)
    uint r;
    asm("v_cvt_pk_bf16_f32 %0, %1, %2" : "=v"(r) : "v"(lo), "v"(hi));
    return r;
}
__device__ inline float bflo(uint w) { return __uint_as_float(w << 16); }
__device__ inline float bfhi(uint w) { return __uint_as_float(w & 0xffff0000u); }

// ---- pack all weights into MFMA B-fragment order (bf16) --------------------
// frag linear index i: e=i&7, lane=(i>>3)&63, rest=i>>9, nt=rest%NT, ks=rest/NT
// k = ks*32 + (lane>>4)*8 + e ; n = nt*16 + (lane&15) ; t = k/CIN ; ci = k%CIN
__global__ void packall_k(
    const float* __restrict__ fe_w1, const float* __restrict__ fe_w2,
    const float* __restrict__ fe_w3, const float* __restrict__ off_w0,
    const float* __restrict__ off_w1, const float* __restrict__ off_w2,
    const float* __restrict__ dcn_off_w, const float* __restrict__ dcn_w,
    ushort* __restrict__ pf1, ushort* __restrict__ pf2, ushort* __restrict__ pf3,
    ushort* __restrict__ po0, ushort* __restrict__ po1, ushort* __restrict__ po2,
    ushort* __restrict__ pow_, ushort* __restrict__ pd) {
    const int y = blockIdx.y;
    int i = blockIdx.x * 256 + threadIdx.x;
    const float* w; ushort* pk; int CIN, NT, KS;
    switch (y) {
        case 0: w = fe_w1;  pk = pf1;  CIN = 16; NT = 1; KS = 5; break;
        case 1: w = fe_w2;  pk = pf2;  CIN = 16; NT = 1; KS = 5; break;
        case 2: w = fe_w3;  pk = pf3;  CIN = 16; NT = 1; KS = 5; break;
        case 3: w = off_w0; pk = po0;  CIN = 32; NT = 1; KS = 9; break;
        case 4: w = off_w1; pk = po1;  CIN = 32; NT = 1; KS = 9; break;
        case 5: w = off_w2; pk = po2;  CIN = 32; NT = 1; KS = 9; break;
        case 6: w = dcn_off_w; pk = pow_; CIN = 16; NT = 9; KS = 5; break;
        default: w = dcn_w; pk = pd;   CIN = 16; NT = 1; KS = 5; break;
    }
    if (i >= KS * NT * 512) return;
    int e = i & 7, lane = (i >> 3) & 63, rest = i >> 9;
    int nt = rest % NT, ks = rest / NT;
    int k = ks * 32 + (lane >> 4) * 8 + e;
    int n = nt * 16 + (lane & 15);
    int t, ci;
    if (CIN == 16) { t = k >> 4; ci = k & 15; } else { t = k >> 5; ci = k & 31; }
    float v = (t < 9) ? w[(n * CIN + ci) * 9 + t] : 0.f;
    pk[i] = f2bf(v);
}

// ---------------- FE conv (CIN=16) on MFMA; both images via z ---------------
// output: cat buffer [pix][32] bf16 at channel offset img*16
template <bool PLANAR>
__launch_bounds__(256)
__global__ void fe_mfma_k(const float* __restrict__ pA, const float* __restrict__ pB,
                          const ushort* __restrict__ catin,
                          const ushort* __restrict__ pack, const float* __restrict__ bias,
                          ushort* __restrict__ catout,
                          int H, int W, int OH, int OW, int pad) {
    __shared__ ushort patch[324 * 16];               // [pos(18x18)][ci]
    const int tid = threadIdx.x;
    const int tx0 = blockIdx.x * 16, ty0 = blockIdx.y * 16;
    const int b = blockIdx.z & 3, img = blockIdx.z >> 2;
    const int bx = tx0 - pad, by = ty0 - pad;
    const int HW = H * W;

    if (PLANAR) {
        const float* inb = (img ? pB : pA) + (size_t)(b * 16) * HW;
        for (int pos = tid; pos < 324; pos += 256) {
            int r = pos / 18, c = pos - r * 18;
            int gy = by + r, gx = bx + c;
            bool ok = (unsigned)gy < (unsigned)H && (unsigned)gx < (unsigned)W;
            int base = gy * W + gx;
            uint o16[8];
#pragma unroll
            for (int ii = 0; ii < 8; ++ii) {
                float lo = ok ? inb[(2 * ii) * HW + base] : 0.f;
                float hi = ok ? inb[(2 * ii + 1) * HW + base] : 0.f;
                o16[ii] = (uint)f2bf(lo) | ((uint)f2bf(hi) << 16);
            }
            *(uint4*)(patch + pos * 16) = *(uint4*)&o16[0];
            *(uint4*)(patch + pos * 16 + 8) = *(uint4*)&o16[4];
        }
    } else {
        for (int c = tid; c < 648; c += 256) {
            int pos = c >> 1, h = c & 1;
            int r = pos / 18, col = pos - r * 18;
            int gy = by + r, gx = bx + col;
            uint4 v = make_uint4(0, 0, 0, 0);
            if ((unsigned)gy < (unsigned)H && (unsigned)gx < (unsigned)W)
                v = *(const uint4*)(catin + ((size_t)(b * H + gy) * W + gx) * 32 + img * 16 + h * 8);
            *(uint4*)(patch + pos * 16 + h * 8) = v;
        }
    }
    __syncthreads();

    const int lane = tid & 63, wv = tid >> 6;
    const int g = lane >> 4, ci0 = (g & 1) * 8, rowx = lane & 15;
    f32x4 acc[4];
    float bv = bias[rowx];
#pragma unroll
    for (int m = 0; m < 4; ++m) acc[m] = f32x4{bv, bv, bv, bv};

#pragma unroll
    for (int ks = 0; ks < 5; ++ks) {
        int t = 2 * ks + (g >> 1);
        int dy = t < 9 ? t / 3 : 0;
        int dx = t < 9 ? t - (t / 3) * 3 : 0;
        bf16x8 a[4];
#pragma unroll
        for (int m = 0; m < 4; ++m) {
            int r = wv * 4 + m + dy, cc = rowx + dx;
            a[m] = *(const bf16x8*)(patch + (r * 18 + cc) * 16 + ci0);
        }
        bf16x8 bfrag = *(const bf16x8*)((const uint4*)pack + ks * 64 + lane);
#pragma unroll
        for (int m = 0; m < 4; ++m)
            acc[m] = __builtin_amdgcn_mfma_f32_16x16x32_bf16(a[m], bfrag, acc[m], 0, 0, 0);
    }

    const int oxb = g * 4;
#pragma unroll
    for (int m = 0; m < 4; ++m) {
        int gy = ty0 + wv * 4 + m;
        if (gy >= OH) continue;
#pragma unroll
        for (int j = 0; j < 4; ++j) {
            int gx = tx0 + oxb + j;
            if (gx < OW)
                catout[((size_t)(b * OH + gy) * OW + gx) * 32 + img * 16 + rowx] =
                    f2bf(fmaxf(acc[m][j], 0.f));
        }
    }
}

// ---------------- offset-feature conv (CIN=32) on MFMA, 3 scales ------------
__launch_bounds__(256)
__global__ void off_mfma_k(const ushort* __restrict__ c0, const ushort* __restrict__ c1,
                           const ushort* __restrict__ c2,
                           const ushort* __restrict__ pk0, const ushort* __restrict__ pk1,
                           const ushort* __restrict__ pk2,
                           const float* __restrict__ b0, const float* __restrict__ b1,
                           const float* __restrict__ b2,
                           ushort* __restrict__ f0, ushort* __restrict__ f1,
                           ushort* __restrict__ f2) {
    const int z = blockIdx.z, s = z >> 2, b = z & 3;
    const int H = 192 - 2 * s, W = H;
    const ushort* cat  = s == 0 ? c0 : (s == 1 ? c1 : c2);
    const ushort* pack = s == 0 ? pk0 : (s == 1 ? pk1 : pk2);
    const float* bias  = s == 0 ? b0 : (s == 1 ? b1 : b2);
    ushort* out        = s == 0 ? f0 : (s == 1 ? f1 : f2);

    __shared__ ushort patch[324 * 32];               // 20.7 KB
    const int tid = threadIdx.x;
    const int tx0 = blockIdx.x * 16, ty0 = blockIdx.y * 16;
    const int bx = tx0 - 1, by = ty0 - 1;

    for (int c = tid; c < 1296; c += 256) {
        int pos = c >> 2, h = c & 3;
        int r = pos / 18, col = pos - r * 18;
        int gy = by + r, gx = bx + col;
        uint4 v = make_uint4(0, 0, 0, 0);
        if ((unsigned)gy < (unsigned)H && (unsigned)gx < (unsigned)W)
            v = *(const uint4*)(cat + ((size_t)(b * H + gy) * W + gx) * 32 + h * 8);
        *(uint4*)(patch + pos * 32 + h * 8) = v;
    }
    __syncthreads();

    const int lane = tid & 63, wv = tid >> 6;
    const int g = lane >> 4, ci0 = g * 8, rowx = lane & 15;
    f32x4 acc[4];
    float bv = bias[rowx];
#pragma unroll
    for (int m = 0; m < 4; ++m) acc[m] = f32x4{bv, bv, bv, bv};

#pragma unroll
    for (int ks = 0; ks < 9; ++ks) {                 // K = 9 taps x 32ci exactly
        int dy = ks / 3, dx = ks - (ks / 3) * 3;
        bf16x8 a[4];
#pragma unroll
        for (int m = 0; m < 4; ++m) {
            int r = wv * 4 + m + dy, cc = rowx + dx;
            a[m] = *(const bf16x8*)(patch + (r * 18 + cc) * 32 + ci0);
        }
        bf16x8 bfrag = *(const bf16x8*)((const uint4*)pack + ks * 64 + lane);
#pragma unroll
        for (int m = 0; m < 4; ++m)
            acc[m] = __builtin_amdgcn_mfma_f32_16x16x32_bf16(a[m], bfrag, acc[m], 0, 0, 0);
    }

    const int oxb = g * 4;
#pragma unroll
    for (int m = 0; m < 4; ++m) {
        int gy = ty0 + wv * 4 + m;
        if (gy >= H) continue;
#pragma unroll
        for (int j = 0; j < 4; ++j) {
            int gx = tx0 + oxb + j;
            if (gx < W)
                out[((size_t)(b * H + gy) * W + gx) * 16 + rowx] = f2bf(fmaxf(acc[m][j], 0.f));
        }
    }
}

// ---- FUSED: offset conv (MFMA) -> LDS offsets -> bilinear sample -> MFMA ----
// Per-row interleave; ks loops at unroll-1. x sampled DIRECTLY from global
// (cat is L2/L3-resident; r12's LDS x-tile staged cache-fit data — dropped).
// ot is wave-private -> NO block barriers; LDS = 19.5 KB for more blocks/CU.
__launch_bounds__(256)
__global__ void dcn_fused_k(const ushort* __restrict__ c0, const ushort* __restrict__ c1,
                            const ushort* __restrict__ c2,
                            const ushort* __restrict__ fb0, const ushort* __restrict__ fb1,
                            const ushort* __restrict__ fb2,
                            const ushort* __restrict__ owPack, const float* __restrict__ ob,
                            const ushort* __restrict__ pd, const float* __restrict__ db,
                            float* __restrict__ o0, float* __restrict__ o1,
                            float* __restrict__ o2) {
    const int z = blockIdx.z;
    const int s = z >> 2, b = z & 3;
    const int H = 192 - 2 * s, W = H;
    const ushort* cat = s == 0 ? c0 : (s == 1 ? c1 : c2);
    const ushort* fb  = s == 0 ? fb0 : (s == 1 ? fb1 : fb2);
    float* out        = s == 0 ? o0 : (s == 1 ? o1 : o2);
    const int HW = H * W;
    const int pixb = b * HW;

    __shared__ ushort ot[4 * 16 * 152];  // per-wave offsets [16 px][152], 19456 B

    const int tid = threadIdx.x;
    const int tx0 = blockIdx.x * 16, ty0 = blockIdx.y * 16;
    const int lane = tid & 63, wv = tid >> 6;
    const int g = lane >> 4, rowx = lane & 15, half = g & 1;
    const int ci0 = half * 8;
    const int px = tx0 + rowx;
    const float bv2 = db[rowx];
    ushort* otw = ot + wv * (16 * 152);
    const ushort* catg = cat + (size_t)pixb * 32 + 16;   // x channels (16..31), wave-uniform base

#pragma unroll 1
    for (int m = 0; m < 4; ++m) {
        const int py = ty0 + wv * 4 + m;

        // A-fragment loader for phase 1 (tap t may be 9 = pad; B is zero there)
        auto loadA = [&](int ks) -> uint4 {
            int t = 2 * ks + (g >> 1);
            int tc = t < 9 ? t : 0;
            int dy = tc / 3, dx = tc - (tc / 3) * 3;
            int gya = ty0 - 1 + wv * 4 + m + dy;
            int gxa = tx0 - 1 + rowx + dx;
            uint4 r = make_uint4(0, 0, 0, 0);
            if ((unsigned)gya < (unsigned)H && (unsigned)gxa < (unsigned)W)
                r = *(const uint4*)(fb + ((size_t)(b * H + gya) * W + gxa) * 16 + ci0);
            return r;
        };

        // ---- phase 1: offset conv for row m (acc[9] only), pipelined ----
        f32x4 acc[9];
#pragma unroll
        for (int n = 0; n < 9; ++n) {
            float bv = ob[n * 16 + rowx];
            acc[n] = f32x4{bv, bv, bv, bv};
        }
        uint4 avc = loadA(0);
#pragma unroll 1
        for (int ks = 0; ks < 5; ++ks) {
            uint4 avn = make_uint4(0, 0, 0, 0);
            if (ks < 4) avn = loadA(ks + 1);
            bf16x8 a = *(bf16x8*)&avc;
            const uint4* bp = (const uint4*)owPack + (size_t)(ks * 9) * 64 + lane;
#pragma unroll
            for (int n = 0; n < 9; ++n) {
                bf16x8 bfrag = *(const bf16x8*)(bp + (size_t)n * 64);
                acc[n] = __builtin_amdgcn_mfma_f32_16x16x32_bf16(a, bfrag, acc[n], 0, 0, 0);
            }
            avc = avn;
        }

        // ---- repack row m into wave-private LDS: [px][tap*16 + dg*2 + comp] ----
#pragma unroll
        for (int n = 0; n < 9; ++n) {
            int ch = n * 16 + rowx;              // 0..143
            int dg = ch / 18;
            int rem = ch - dg * 18;
            int col = (rem >> 1) * 16 + dg * 2 + (rem & 1);
            uint p01 = pkbf(acc[n][0], acc[n][1]);
            uint p23 = pkbf(acc[n][2], acc[n][3]);
            otw[(g * 4 + 0) * 152 + col] = (ushort)p01;
            otw[(g * 4 + 1) * 152 + col] = (ushort)(p01 >> 16);
            otw[(g * 4 + 2) * 152 + col] = (ushort)p23;
            otw[(g * 4 + 3) * 152 + col] = (ushort)(p23 >> 16);
        }

        // offsets loader for phase 2
        auto loadOV = [&](int ks) -> uint4 {
            int t = 2 * ks + (g >> 1);
            uint4 r = make_uint4(0, 0, 0, 0);
            if (t < 9) r = *(const uint4*)(otw + rowx * 152 + t * 16 + half * 8);
            return r;
        };

        // ---- phase 2: sample from global + deform-conv MFMA, pipelined ----
        f32x4 acc2 = f32x4{bv2, bv2, bv2, bv2};
        uint4 ovc = loadOV(0);
#pragma unroll 1
        for (int ks = 0; ks < 5; ++ks) {
            uint4 ovn = make_uint4(0, 0, 0, 0);
            if (ks < 4) ovn = loadOV(ks + 1);
            const int t = 2 * ks + (g >> 1);
            const bool tv = (t < 9);
            const int t3 = t / 3;
            const float pyk = (float)(py + (tv ? t3 : 0) - 1);
            const float pxk = (float)(px + (tv ? t - t3 * 3 : 0) - 1);

            uint a2[4];
            if (tv) {
                uint ovv[4] = {ovc.x, ovc.y, ovc.z, ovc.w};
#pragma unroll
                for (int d = 0; d < 4; ++d) {
                    const int dgA = half * 4 + d;
                    uint u = ovv[d];
                    float sy = pyk + bflo(u);
                    float sx = pxk + bfhi(u);
                    float fy = floorf(sy), fx = floorf(sx);
                    int y0 = (int)fy, x0 = (int)fx;
                    float wy = sy - fy, wx = sx - fx;
                    bool y0v = (unsigned)y0 < (unsigned)H;
                    bool y1v = (unsigned)(y0 + 1) < (unsigned)H;
                    bool x0v = (unsigned)x0 < (unsigned)W;
                    bool x1v = (unsigned)(x0 + 1) < (unsigned)W;
                    int y0c = min(max(y0, 0), H - 1);
                    int y1c = min(max(y0 + 1, 0), H - 1);
                    int x0c = min(max(x0, 0), W - 1);
                    int x1c = min(max(x0 + 1, 0), W - 1);
                    int r0 = y0c * W, r1 = y1c * W;
                    uint u00 = *(const uint*)(catg + (size_t)((r0 + x0c) * 32 + 2 * dgA));
                    uint u01 = *(const uint*)(catg + (size_t)((r0 + x1c) * 32 + 2 * dgA));
                    uint u10 = *(const uint*)(catg + (size_t)((r1 + x0c) * 32 + 2 * dgA));
                    uint u11 = *(const uint*)(catg + (size_t)((r1 + x1c) * 32 + 2 * dgA));
                    u00 = (y0v && x0v) ? u00 : 0u;
                    u01 = (y0v && x1v) ? u01 : 0u;
                    u10 = (y1v && x0v) ? u10 : 0u;
                    u11 = (y1v && x1v) ? u11 : 0u;
                    float wy1 = 1.f - wy, wx1 = 1.f - wx;
                    float w00 = wy1 * wx1, w01 = wy1 * wx, w10 = wy * wx1, w11 = wy * wx;
                    float s0 = w00 * bflo(u00) + w01 * bflo(u01) + w10 * bflo(u10) + w11 * bflo(u11);
                    float s1 = w00 * bfhi(u00) + w01 * bfhi(u01) + w10 * bfhi(u10) + w11 * bfhi(u11);
                    a2[d] = pkbf(s0, s1);
                }
            } else {
                a2[0] = a2[1] = a2[2] = a2[3] = 0u;
            }
            uint4 av = make_uint4(a2[0], a2[1], a2[2], a2[3]);
            bf16x8 af = *(bf16x8*)&av;
            bf16x8 dfrag = *(const bf16x8*)((const uint4*)pd + ks * 64 + lane);
            acc2 = __builtin_amdgcn_mfma_f32_16x16x32_bf16(af, dfrag, acc2, 0, 0, 0);
            ovc = ovn;
        }

        // ---- store row m: out channel = rowx, image col = g*4+j ----
        if (py < H) {
            float* op = out + (size_t)(b * 16 + rowx) * HW + (size_t)py * W;
#pragma unroll
            for (int j = 0; j < 4; ++j) {
                int gx2 = tx0 + g * 4 + j;
                if (gx2 < W) op[gx2] = acc2[j];
            }
        }
    }
}

// ---------------------------------------------------------------------------
extern "C" void kernel_launch(void* const* d_in, const int* in_sizes, int n_in,
                              void* d_out, int out_size, void* d_ws, size_t ws_size,
                              hipStream_t stream) {
    const float* ref_image = (const float*)d_in[0];
    const float* unreg_image = (const float*)d_in[1];
    const float* fe_w1 = (const float*)d_in[2];
    const float* fe_b1 = (const float*)d_in[3];
    const float* fe_w2 = (const float*)d_in[4];
    const float* fe_b2 = (const float*)d_in[5];
    const float* fe_w3 = (const float*)d_in[6];
    const float* fe_b3 = (const float*)d_in[7];
    const float* off_w0 = (const float*)d_in[8];
    const float* off_b0 = (const float*)d_in[9];
    const float* off_w1 = (const float*)d_in[10];
    const float* off_b1 = (const float*)d_in[11];
    const float* off_w2 = (const float*)d_in[12];
    const float* off_b2 = (const float*)d_in[13];
    const float* dcn_off_w = (const float*)d_in[14];
    const float* dcn_off_b = (const float*)d_in[15];
    const float* dcn_w = (const float*)d_in[16];
    const float* dcn_b = (const float*)d_in[17];

    const size_t pix[3] = {4ul * 192 * 192, 4ul * 190 * 190, 4ul * 188 * 188};
    const size_t szf[3] = {pix[0] * 16, pix[1] * 16, pix[2] * 16};

    size_t o = 0;
    auto take = [&](size_t bytes) {
        void* r = (char*)d_ws + o;
        o += (bytes + 255) & ~(size_t)255;
        return r;
    };
    ushort* cat[3]; ushort* fb[3];
    ushort* pf[3]; ushort* po[3]; ushort* owPack; ushort* pd;
    for (int s = 0; s < 3; ++s) cat[s] = (ushort*)take(pix[s] * 32 * 2);
    for (int s = 0; s < 3; ++s) fb[s] = (ushort*)take(pix[s] * 16 * 2);
    for (int s = 0; s < 3; ++s) pf[s] = (ushort*)take(2560 * 2);
    for (int s = 0; s < 3; ++s) po[s] = (ushort*)take(4608 * 2);
    owPack = (ushort*)take(23040 * 2);
    pd = (ushort*)take(2560 * 2);

    float* out0 = (float*)d_out;
    float* out1 = out0 + szf[0];
    float* out2 = out1 + szf[1];

    dim3 blk(256);

    packall_k<<<dim3(90, 8), blk, 0, stream>>>(
        fe_w1, fe_w2, fe_w3, off_w0, off_w1, off_w2, dcn_off_w, dcn_w,
        pf[0], pf[1], pf[2], po[0], po[1], po[2], owPack, pd);

    // FE convs (both images per launch), output -> cat buffers
    fe_mfma_k<true><<<dim3(12, 12, 8), blk, 0, stream>>>(
        ref_image, unreg_image, nullptr, pf[0], fe_b1, cat[0], 192, 192, 192, 192, 1);
    fe_mfma_k<false><<<dim3(12, 12, 8), blk, 0, stream>>>(
        nullptr, nullptr, cat[0], pf[1], fe_b2, cat[1], 192, 192, 190, 190, 0);
    fe_mfma_k<false><<<dim3(12, 12, 8), blk, 0, stream>>>(
        nullptr, nullptr, cat[1], pf[2], fe_b3, cat[2], 190, 190, 188, 188, 0);

    // offset-feature convs (all scales)
    off_mfma_k<<<dim3(12, 12, 12), blk, 0, stream>>>(
        cat[0], cat[1], cat[2], po[0], po[1], po[2],
        off_b0, off_b1, off_b2, fb[0], fb[1], fb[2]);

    // fused dcn-offset conv + deformable conv (all scales)
    dcn_fused_k<<<dim3(12, 12, 12), blk, 0, stream>>>(
        cat[0], cat[1], cat[2], fb[0], fb[1], fb[2],
        owPack, dcn_off_b, pd, dcn_b, out0, out1, out2);
}

// Round 14
// 198.875 us; speedup vs baseline: 1.6657x; 1.6657x over previous
//
#include <hip/hip_runtime.h>

typedef unsigned int uint;
typedef unsigned short ushort;
typedef __attribute__((ext_vector_type(8))) short bf16x8;
typedef __attribute__((ext_vector_type(4))) float f32x4;

__device__ inline ushort f2bf(float f) {           // f32 -> bf16 RNE
    uint u = __float_as_uint(f);
    u += 0x7fff + ((u >> 16) & 1);
    return (ushort)(u >> 16);
}
__device__ inline uint pkbf(float lo, float hi) {  // 2xf32 -> packed bf16 pair (RNE)
    uint r;
    asm("v_cvt_pk_bf16_f32 %0, %1, %2" : "=v"(r) : "v"(lo), "v"(hi));
    return r;
}
__device__ inline float bflo(uint w) { return __uint_as_float(w << 16); }
__device__ inline float bfhi(uint w) { return __uint_as_float(w & 0xffff0000u); }

// ---- pack all weights into MFMA B-fragment order (bf16) --------------------
__global__ void packall_k(
    const float* __restrict__ fe_w1, const float* __restrict__ fe_w2,
    const float* __restrict__ fe_w3, const float* __restrict__ off_w0,
    const float* __restrict__ off_w1, const float* __restrict__ off_w2,
    const float* __restrict__ dcn_off_w, const float* __restrict__ dcn_w,
    ushort* __restrict__ pf1, ushort* __restrict__ pf2, ushort* __restrict__ pf3,
    ushort* __restrict__ po0, ushort* __restrict__ po1, ushort* __restrict__ po2,
    ushort* __restrict__ pow_, ushort* __restrict__ pd) {
    const int y = blockIdx.y;
    int i = blockIdx.x * 256 + threadIdx.x;
    const float* w; ushort* pk; int CIN, NT, KS;
    switch (y) {
        case 0: w = fe_w1;  pk = pf1;  CIN = 16; NT = 1; KS = 5; break;
        case 1: w = fe_w2;  pk = pf2;  CIN = 16; NT = 1; KS = 5; break;
        case 2: w = fe_w3;  pk = pf3;  CIN = 16; NT = 1; KS = 5; break;
        case 3: w = off_w0; pk = po0;  CIN = 32; NT = 1; KS = 9; break;
        case 4: w = off_w1; pk = po1;  CIN = 32; NT = 1; KS = 9; break;
        case 5: w = off_w2; pk = po2;  CIN = 32; NT = 1; KS = 9; break;
        case 6: w = dcn_off_w; pk = pow_; CIN = 16; NT = 9; KS = 5; break;
        default: w = dcn_w; pk = pd;   CIN = 16; NT = 1; KS = 5; break;
    }
    if (i >= KS * NT * 512) return;
    int e = i & 7, lane = (i >> 3) & 63, rest = i >> 9;
    int nt = rest % NT, ks = rest / NT;
    int k = ks * 32 + (lane >> 4) * 8 + e;
    int n = nt * 16 + (lane & 15);
    int t, ci;
    if (CIN == 16) { t = k >> 4; ci = k & 15; } else { t = k >> 5; ci = k & 31; }
    float v = (t < 9) ? w[(n * CIN + ci) * 9 + t] : 0.f;
    pk[i] = f2bf(v);
}

// ---------------- FE conv (CIN=16) on MFMA; both images via z ---------------
template <bool PLANAR>
__launch_bounds__(256)
__global__ void fe_mfma_k(const float* __restrict__ pA, const float* __restrict__ pB,
                          const ushort* __restrict__ catin,
                          const ushort* __restrict__ pack, const float* __restrict__ bias,
                          ushort* __restrict__ catout,
                          int H, int W, int OH, int OW, int pad) {
    __shared__ ushort patch[324 * 16];               // [pos(18x18)][ci]
    const int tid = threadIdx.x;
    const int tx0 = blockIdx.x * 16, ty0 = blockIdx.y * 16;
    const int b = blockIdx.z & 3, img = blockIdx.z >> 2;
    const int bx = tx0 - pad, by = ty0 - pad;
    const int HW = H * W;

    if (PLANAR) {
        const float* inb = (img ? pB : pA) + (size_t)(b * 16) * HW;
        for (int pos = tid; pos < 324; pos += 256) {
            int r = pos / 18, c = pos - r * 18;
            int gy = by + r, gx = bx + c;
            bool ok = (unsigned)gy < (unsigned)H && (unsigned)gx < (unsigned)W;
            int base = gy * W + gx;
            uint o16[8];
#pragma unroll
            for (int ii = 0; ii < 8; ++ii) {
                float lo = ok ? inb[(2 * ii) * HW + base] : 0.f;
                float hi = ok ? inb[(2 * ii + 1) * HW + base] : 0.f;
                o16[ii] = (uint)f2bf(lo) | ((uint)f2bf(hi) << 16);
            }
            *(uint4*)(patch + pos * 16) = *(uint4*)&o16[0];
            *(uint4*)(patch + pos * 16 + 8) = *(uint4*)&o16[4];
        }
    } else {
        for (int c = tid; c < 648; c += 256) {
            int pos = c >> 1, h = c & 1;
            int r = pos / 18, col = pos - r * 18;
            int gy = by + r, gx = bx + col;
            uint4 v = make_uint4(0, 0, 0, 0);
            if ((unsigned)gy < (unsigned)H && (unsigned)gx < (unsigned)W)
                v = *(const uint4*)(catin + ((size_t)(b * H + gy) * W + gx) * 32 + img * 16 + h * 8);
            *(uint4*)(patch + pos * 16 + h * 8) = v;
        }
    }
    __syncthreads();

    const int lane = tid & 63, wv = tid >> 6;
    const int g = lane >> 4, ci0 = (g & 1) * 8, rowx = lane & 15;
    f32x4 acc[4];
    float bv = bias[rowx];
#pragma unroll
    for (int m = 0; m < 4; ++m) acc[m] = f32x4{bv, bv, bv, bv};

#pragma unroll
    for (int ks = 0; ks < 5; ++ks) {
        int t = 2 * ks + (g >> 1);
        int dy = t < 9 ? t / 3 : 0;
        int dx = t < 9 ? t - (t / 3) * 3 : 0;
        bf16x8 a[4];
#pragma unroll
        for (int m = 0; m < 4; ++m) {
            int r = wv * 4 + m + dy, cc = rowx + dx;
            a[m] = *(const bf16x8*)(patch + (r * 18 + cc) * 16 + ci0);
        }
        bf16x8 bfrag = *(const bf16x8*)((const uint4*)pack + ks * 64 + lane);
#pragma unroll
        for (int m = 0; m < 4; ++m)
            acc[m] = __builtin_amdgcn_mfma_f32_16x16x32_bf16(a[m], bfrag, acc[m], 0, 0, 0);
    }

    const int oxb = g * 4;
#pragma unroll
    for (int m = 0; m < 4; ++m) {
        int gy = ty0 + wv * 4 + m;
        if (gy >= OH) continue;
#pragma unroll
        for (int j = 0; j < 4; ++j) {
            int gx = tx0 + oxb + j;
            if (gx < OW)
                catout[((size_t)(b * OH + gy) * OW + gx) * 32 + img * 16 + rowx] =
                    f2bf(fmaxf(acc[m][j], 0.f));
        }
    }
}

// ---------------- offset-feature conv (CIN=32) on MFMA, 3 scales ------------
__launch_bounds__(256)
__global__ void off_mfma_k(const ushort* __restrict__ c0, const ushort* __restrict__ c1,
                           const ushort* __restrict__ c2,
                           const ushort* __restrict__ pk0, const ushort* __restrict__ pk1,
                           const ushort* __restrict__ pk2,
                           const float* __restrict__ b0, const float* __restrict__ b1,
                           const float* __restrict__ b2,
                           ushort* __restrict__ f0, ushort* __restrict__ f1,
                           ushort* __restrict__ f2) {
    const int z = blockIdx.z, s = z >> 2, b = z & 3;
    const int H = 192 - 2 * s, W = H;
    const ushort* cat  = s == 0 ? c0 : (s == 1 ? c1 : c2);
    const ushort* pack = s == 0 ? pk0 : (s == 1 ? pk1 : pk2);
    const float* bias  = s == 0 ? b0 : (s == 1 ? b1 : b2);
    ushort* out        = s == 0 ? f0 : (s == 1 ? f1 : f2);

    __shared__ ushort patch[324 * 32];               // 20.7 KB
    const int tid = threadIdx.x;
    const int tx0 = blockIdx.x * 16, ty0 = blockIdx.y * 16;
    const int bx = tx0 - 1, by = ty0 - 1;

    for (int c = tid; c < 1296; c += 256) {
        int pos = c >> 2, h = c & 3;
        int r = pos / 18, col = pos - r * 18;
        int gy = by + r, gx = bx + col;
        uint4 v = make_uint4(0, 0, 0, 0);
        if ((unsigned)gy < (unsigned)H && (unsigned)gx < (unsigned)W)
            v = *(const uint4*)(cat + ((size_t)(b * H + gy) * W + gx) * 32 + h * 8);
        *(uint4*)(patch + pos * 32 + h * 8) = v;
    }
    __syncthreads();

    const int lane = tid & 63, wv = tid >> 6;
    const int g = lane >> 4, ci0 = g * 8, rowx = lane & 15;
    f32x4 acc[4];
    float bv = bias[rowx];
#pragma unroll
    for (int m = 0; m < 4; ++m) acc[m] = f32x4{bv, bv, bv, bv};

#pragma unroll
    for (int ks = 0; ks < 9; ++ks) {                 // K = 9 taps x 32ci exactly
        int dy = ks / 3, dx = ks - (ks / 3) * 3;
        bf16x8 a[4];
#pragma unroll
        for (int m = 0; m < 4; ++m) {
            int r = wv * 4 + m + dy, cc = rowx + dx;
            a[m] = *(const bf16x8*)(patch + (r * 18 + cc) * 32 + ci0);
        }
        bf16x8 bfrag = *(const bf16x8*)((const uint4*)pack + ks * 64 + lane);
#pragma unroll
        for (int m = 0; m < 4; ++m)
            acc[m] = __builtin_amdgcn_mfma_f32_16x16x32_bf16(a[m], bfrag, acc[m], 0, 0, 0);
    }

    const int oxb = g * 4;
#pragma unroll
    for (int m = 0; m < 4; ++m) {
        int gy = ty0 + wv * 4 + m;
        if (gy >= H) continue;
#pragma unroll
        for (int j = 0; j < 4; ++j) {
            int gx = tx0 + oxb + j;
            if (gx < W)
                out[((size_t)(b * H + gy) * W + gx) * 16 + rowx] = f2bf(fmaxf(acc[m][j], 0.f));
        }
    }
}

// ---- FUSED: offset conv (MFMA) -> LDS offsets -> bilinear sample -> MFMA ----
// r12 structure (xtu x-tile in LDS, wave-private ot, no barriers in row loop)
// + ROW-LEVEL software pipeline: row m+1's 5 A-fragment global loads are
// issued BEFORE row m's VALU-heavy sampling phase (T14 issue-early), and its
// 45 offset-conv MFMAs run after, on long-landed data. otw is read (phase 2,
// row m) strictly before being overwritten (repack, row m+1) -> no extra LDS.
__launch_bounds__(256)
__global__ void dcn_fused_k(const ushort* __restrict__ c0, const ushort* __restrict__ c1,
                            const ushort* __restrict__ c2,
                            const ushort* __restrict__ fb0, const ushort* __restrict__ fb1,
                            const ushort* __restrict__ fb2,
                            const ushort* __restrict__ owPack, const float* __restrict__ ob,
                            const ushort* __restrict__ pd, const float* __restrict__ db,
                            float* __restrict__ o0, float* __restrict__ o1,
                            float* __restrict__ o2) {
    const int z = blockIdx.z;
    const int s = z >> 2, b = z & 3;
    const int H = 192 - 2 * s, W = H;
    const ushort* cat = s == 0 ? c0 : (s == 1 ? c1 : c2);
    const ushort* fb  = s == 0 ? fb0 : (s == 1 ? fb1 : fb2);
    float* out        = s == 0 ? o0 : (s == 1 ? o1 : o2);
    const int HW = H * W;
    const size_t pixb = (size_t)b * HW;

    __shared__ uint   xtu[8 * 484];      // x tile (bf16 ch-pairs), halo 3, 15488 B
    __shared__ ushort ot[4 * 16 * 152];  // per-wave offsets [16 px][152], 19456 B

    const int tid = threadIdx.x;
    const int tx0 = blockIdx.x * 16, ty0 = blockIdx.y * 16;

    // ---- stage x tile (halo 3, bf16 ch-pairs) ----
    {
        const int bx3 = tx0 - 3, by3 = ty0 - 3;
        for (int pos = tid; pos < 484; pos += 256) {
            int r = pos / 22, c = pos - r * 22;
            int gy2 = by3 + r, gx2 = bx3 + c;
            uint4 va = make_uint4(0, 0, 0, 0), vb = va;
            if ((unsigned)gy2 < (unsigned)H && (unsigned)gx2 < (unsigned)W) {
                const ushort* src = cat + (pixb + gy2 * W + gx2) * 32 + 16;
                va = *(const uint4*)src;
                vb = *(const uint4*)(src + 8);
            }
            xtu[0 * 484 + pos] = va.x; xtu[1 * 484 + pos] = va.y;
            xtu[2 * 484 + pos] = va.z; xtu[3 * 484 + pos] = va.w;
            xtu[4 * 484 + pos] = vb.x; xtu[5 * 484 + pos] = vb.y;
            xtu[6 * 484 + pos] = vb.z; xtu[7 * 484 + pos] = vb.w;
        }
    }
    __syncthreads();

    const int lane = tid & 63, wv = tid >> 6;
    const int g = lane >> 4, rowx = lane & 15, half = g & 1;
    const int ci0 = half * 8;
    const int px = tx0 + rowx;
    const float bv2 = db[rowx];
    ushort* otw = ot + wv * (16 * 152);

    // A-fragment loader: tap t = 2ks+(g>>1) may be 9 = pad (B zero there)
    auto loadA = [&](int ks, int mrow) -> uint4 {
        int t = 2 * ks + (g >> 1);
        int tc = t < 9 ? t : 0;
        int dy = tc / 3, dx = tc - (tc / 3) * 3;
        int gya = ty0 - 1 + wv * 4 + mrow + dy;
        int gxa = tx0 - 1 + rowx + dx;
        uint4 r = make_uint4(0, 0, 0, 0);
        if ((unsigned)gya < (unsigned)H && (unsigned)gxa < (unsigned)W)
            r = *(const uint4*)(fb + ((size_t)(b * H + gya) * W + gxa) * 16 + ci0);
        return r;
    };

    // 45 offset-conv MFMAs for one row, A's preloaded (ks select is
    // wave-uniform -> scalar branch; no runtime-indexed register arrays).
    auto mfma45 = [&](uint4 a0, uint4 a1, uint4 a2c, uint4 a3, uint4 a4,
                      f32x4 (&acc)[9]) {
#pragma unroll
        for (int n = 0; n < 9; ++n) {
            float bv = ob[n * 16 + rowx];
            acc[n] = f32x4{bv, bv, bv, bv};
        }
#pragma unroll 1
        for (int ks = 0; ks < 5; ++ks) {
            uint4 avv = ks == 0 ? a0 : ks == 1 ? a1 : ks == 2 ? a2c : ks == 3 ? a3 : a4;
            bf16x8 a = *(bf16x8*)&avv;
            const uint4* bp = (const uint4*)owPack + (size_t)(ks * 9) * 64 + lane;
#pragma unroll
            for (int n = 0; n < 9; ++n) {
                bf16x8 bfrag = *(const bf16x8*)(bp + (size_t)n * 64);
                acc[n] = __builtin_amdgcn_mfma_f32_16x16x32_bf16(a, bfrag, acc[n], 0, 0, 0);
            }
        }
    };

    // repack one row's offset C-fragments into otw [px][tap*16 + dg*2 + comp]
    auto repack = [&](f32x4 (&acc)[9]) {
#pragma unroll
        for (int n = 0; n < 9; ++n) {
            int ch = n * 16 + rowx;              // 0..143
            int dg = ch / 18;
            int rem = ch - dg * 18;
            int col = (rem >> 1) * 16 + dg * 2 + (rem & 1);
            uint p01 = pkbf(acc[n][0], acc[n][1]);
            uint p23 = pkbf(acc[n][2], acc[n][3]);
            otw[(g * 4 + 0) * 152 + col] = (ushort)p01;
            otw[(g * 4 + 1) * 152 + col] = (ushort)(p01 >> 16);
            otw[(g * 4 + 2) * 152 + col] = (ushort)p23;
            otw[(g * 4 + 3) * 152 + col] = (ushort)(p23 >> 16);
        }
    };

    // ---- prologue: compute row 0's offsets ----
    {
        uint4 a0 = loadA(0, 0), a1 = loadA(1, 0), a2c = loadA(2, 0),
              a3 = loadA(3, 0), a4 = loadA(4, 0);
        f32x4 acc[9];
        mfma45(a0, a1, a2c, a3, a4, acc);
        repack(acc);
    }

#pragma unroll 1
    for (int m = 0; m < 4; ++m) {
        const int py = ty0 + wv * 4 + m;
        const int mn = m + 1;

        // ---- issue next row's A-fragment loads (in flight during phase 2) --
        uint4 na0, na1, na2, na3, na4;
        if (mn < 4) {
            na0 = loadA(0, mn); na1 = loadA(1, mn); na2 = loadA(2, mn);
            na3 = loadA(3, mn); na4 = loadA(4, mn);
        }

        // offsets loader for phase 2
        auto loadOV = [&](int ks) -> uint4 {
            int t = 2 * ks + (g >> 1);
            uint4 r = make_uint4(0, 0, 0, 0);
            if (t < 9) r = *(const uint4*)(otw + rowx * 152 + t * 16 + half * 8);
            return r;
        };

        // ---- phase 2: sample + deform-conv MFMA for row m ----
        f32x4 acc2 = f32x4{bv2, bv2, bv2, bv2};
        uint4 ovc = loadOV(0);
#pragma unroll 1
        for (int ks = 0; ks < 5; ++ks) {
            uint4 ovn = make_uint4(0, 0, 0, 0);
            if (ks < 4) ovn = loadOV(ks + 1);
            const int t = 2 * ks + (g >> 1);
            const bool tv = (t < 9);
            const int t3 = t / 3;
            const float pyk = (float)(py + (tv ? t3 : 0) - 1);
            const float pxk = (float)(px + (tv ? t - t3 * 3 : 0) - 1);

            uint a2[4];
            if (tv) {
                uint ovv[4] = {ovc.x, ovc.y, ovc.z, ovc.w};
#pragma unroll
                for (int d = 0; d < 4; ++d) {
                    const int dgA = half * 4 + d;
                    uint u = ovv[d];
                    float sy = pyk + bflo(u);
                    float sx = pxk + bfhi(u);
                    float fy = floorf(sy), fx = floorf(sx);
                    int y0 = (int)fy, x0 = (int)fx;
                    float wy = sy - fy, wx = sx - fx;
                    float wy1 = 1.f - wy, wx1 = 1.f - wx;
                    float w00 = wy1 * wx1, w01 = wy1 * wx, w10 = wy * wx1, w11 = wy * wx;
                    int ly = y0 - (ty0 - 3), lx = x0 - (tx0 - 3);
                    float2 v00, v01, v10, v11;
                    if ((unsigned)ly <= 20u && (unsigned)lx <= 20u) {
                        const uint* tt = &xtu[dgA * 484 + ly * 22 + lx];
                        uint u00 = tt[0], u01 = tt[1], u10 = tt[22], u11 = tt[23];
                        v00 = make_float2(bflo(u00), bfhi(u00));
                        v01 = make_float2(bflo(u01), bfhi(u01));
                        v10 = make_float2(bflo(u10), bfhi(u10));
                        v11 = make_float2(bflo(u11), bfhi(u11));
                    } else {
                        v00 = v01 = v10 = v11 = make_float2(0.f, 0.f);
                        bool y0v = (unsigned)y0 < (unsigned)H;
                        bool y1v = (unsigned)(y0 + 1) < (unsigned)H;
                        bool x0v = (unsigned)x0 < (unsigned)W;
                        bool x1v = (unsigned)(x0 + 1) < (unsigned)W;
                        const ushort* cg = cat + (pixb + (size_t)y0 * W + x0) * 32 + 16 + 2 * dgA;
                        if (y0v && x0v) { uint uu = *(const uint*)cg;                 v00 = make_float2(bflo(uu), bfhi(uu)); }
                        if (y0v && x1v) { uint uu = *(const uint*)(cg + 32);          v01 = make_float2(bflo(uu), bfhi(uu)); }
                        if (y1v && x0v) { uint uu = *(const uint*)(cg + 32 * W);      v10 = make_float2(bflo(uu), bfhi(uu)); }
                        if (y1v && x1v) { uint uu = *(const uint*)(cg + 32 * W + 32); v11 = make_float2(bflo(uu), bfhi(uu)); }
                    }
                    float s0 = w00 * v00.x + w01 * v01.x + w10 * v10.x + w11 * v11.x;
                    float s1 = w00 * v00.y + w01 * v01.y + w10 * v10.y + w11 * v11.y;
                    a2[d] = pkbf(s0, s1);
                }
            } else {
                a2[0] = a2[1] = a2[2] = a2[3] = 0u;
            }
            uint4 av = make_uint4(a2[0], a2[1], a2[2], a2[3]);
            bf16x8 af = *(bf16x8*)&av;
            bf16x8 dfrag = *(const bf16x8*)((const uint4*)pd + ks * 64 + lane);
            acc2 = __builtin_amdgcn_mfma_f32_16x16x32_bf16(af, dfrag, acc2, 0, 0, 0);
            ovc = ovn;
        }

        // ---- store row m: out channel = rowx, image col = g*4+j ----
        if (py < H) {
            float* op = out + (size_t)(b * 16 + rowx) * HW + (size_t)py * W;
#pragma unroll
            for (int j = 0; j < 4; ++j) {
                int gx2 = tx0 + g * 4 + j;
                if (gx2 < W) op[gx2] = acc2[j];
            }
        }

        // ---- phase 1 for row m+1 (A's loaded long ago) + repack ----
        if (mn < 4) {
            f32x4 acc[9];
            mfma45(na0, na1, na2, na3, na4, acc);
            repack(acc);
        }
    }
}

// ---------------------------------------------------------------------------
extern "C" void kernel_launch(void* const* d_in, const int* in_sizes, int n_in,
                              void* d_out, int out_size, void* d_ws, size_t ws_size,
                              hipStream_t stream) {
    const float* ref_image = (const float*)d_in[0];
    const float* unreg_image = (const float*)d_in[1];
    const float* fe_w1 = (const float*)d_in[2];
    const float* fe_b1 = (const float*)d_in[3];
    const float* fe_w2 = (const float*)d_in[4];
    const float* fe_b2 = (const float*)d_in[5];
    const float* fe_w3 = (const float*)d_in[6];
    const float* fe_b3 = (const float*)d_in[7];
    const float* off_w0 = (const float*)d_in[8];
    const float* off_b0 = (const float*)d_in[9];
    const float* off_w1 = (const float*)d_in[10];
    const float* off_b1 = (const float*)d_in[11];
    const float* off_w2 = (const float*)d_in[12];
    const float* off_b2 = (const float*)d_in[13];
    const float* dcn_off_w = (const float*)d_in[14];
    const float* dcn_off_b = (const float*)d_in[15];
    const float* dcn_w = (const float*)d_in[16];
    const float* dcn_b = (const float*)d_in[17];

    const size_t pix[3] = {4ul * 192 * 192, 4ul * 190 * 190, 4ul * 188 * 188};
    const size_t szf[3] = {pix[0] * 16, pix[1] * 16, pix[2] * 16};

    size_t o = 0;
    auto take = [&](size_t bytes) {
        void* r = (char*)d_ws + o;
        o += (bytes + 255) & ~(size_t)255;
        return r;
    };
    ushort* cat[3]; ushort* fb[3];
    ushort* pf[3]; ushort* po[3]; ushort* owPack; ushort* pd;
    for (int s = 0; s < 3; ++s) cat[s] = (ushort*)take(pix[s] * 32 * 2);
    for (int s = 0; s < 3; ++s) fb[s] = (ushort*)take(pix[s] * 16 * 2);
    for (int s = 0; s < 3; ++s) pf[s] = (ushort*)take(2560 * 2);
    for (int s = 0; s < 3; ++s) po[s] = (ushort*)take(4608 * 2);
    owPack = (ushort*)take(23040 * 2);
    pd = (ushort*)take(2560 * 2);

    float* out0 = (float*)d_out;
    float* out1 = out0 + szf[0];
    float* out2 = out1 + szf[1];

    dim3 blk(256);

    packall_k<<<dim3(90, 8), blk, 0, stream>>>(
        fe_w1, fe_w2, fe_w3, off_w0, off_w1, off_w2, dcn_off_w, dcn_w,
        pf[0], pf[1], pf[2], po[0], po[1], po[2], owPack, pd);

    // FE convs (both images per launch), output -> cat buffers
    fe_mfma_k<true><<<dim3(12, 12, 8), blk, 0, stream>>>(
        ref_image, unreg_image, nullptr, pf[0], fe_b1, cat[0], 192, 192, 192, 192, 1);
    fe_mfma_k<false><<<dim3(12, 12, 8), blk, 0, stream>>>(
        nullptr, nullptr, cat[0], pf[1], fe_b2, cat[1], 192, 192, 190, 190, 0);
    fe_mfma_k<false><<<dim3(12, 12, 8), blk, 0, stream>>>(
        nullptr, nullptr, cat[1], pf[2], fe_b3, cat[2], 190, 190, 188, 188, 0);

    // offset-feature convs (all scales)
    off_mfma_k<<<dim3(12, 12, 12), blk, 0, stream>>>(
        cat[0], cat[1], cat[2], po[0], po[1], po[2],
        off_b0, off_b1, off_b2, fb[0], fb[1], fb[2]);

    // fused dcn-offset conv + deformable conv (all scales)
    dcn_fused_k<<<dim3(12, 12, 12), blk, 0, stream>>>(
        cat[0], cat[1], cat[2], fb[0], fb[1], fb[2],
        owPack, dcn_off_b, pd, dcn_b, out0, out1, out2);
}

// Round 15
// 175.536 us; speedup vs baseline: 1.8871x; 1.1330x over previous
//
#include <hip/hip_runtime.h>

typedef unsigned int uint;
typedef unsigned short ushort;
typedef __attribute__((ext_vector_type(8))) short bf16x8;
typedef __attribute__((ext_vector_type(4))) float f32x4;

__device__ inline ushort f2bf(float f) {           // f32 -> bf16 RNE
    uint u = __float_as_uint(f);
    u += 0x7fff + ((u >> 16) & 1);
    return (ushort)(u >> 16);
}
__device__ inline float bflo(uint w) { return __uint_as_float(w << 16); }
__device__ inline float bfhi(uint w) { return __uint_as_float(w & 0xffff0000u); }

// ---- pack all weights into MFMA B-fragment order (bf16) --------------------
// frag linear index i: e=i&7, lane=(i>>3)&63, rest=i>>9, nt=rest%NT, ks=rest/NT
// k = ks*32 + (lane>>4)*8 + e ; n = nt*16 + (lane&15) ; t = k/CIN ; ci = k%CIN
__global__ void packall_k(
    const float* __restrict__ fe_w1, const float* __restrict__ fe_w2,
    const float* __restrict__ fe_w3, const float* __restrict__ off_w0,
    const float* __restrict__ off_w1, const float* __restrict__ off_w2,
    const float* __restrict__ dcn_off_w, const float* __restrict__ dcn_w,
    ushort* __restrict__ pf1, ushort* __restrict__ pf2, ushort* __restrict__ pf3,
    ushort* __restrict__ po0, ushort* __restrict__ po1, ushort* __restrict__ po2,
    ushort* __restrict__ pow_, ushort* __restrict__ pd) {
    const int y = blockIdx.y;
    int i = blockIdx.x * 256 + threadIdx.x;
    const float* w; ushort* pk; int CIN, NT, KS;
    switch (y) {
        case 0: w = fe_w1;  pk = pf1;  CIN = 16; NT = 1; KS = 5; break;
        case 1: w = fe_w2;  pk = pf2;  CIN = 16; NT = 1; KS = 5; break;
        case 2: w = fe_w3;  pk = pf3;  CIN = 16; NT = 1; KS = 5; break;
        case 3: w = off_w0; pk = po0;  CIN = 32; NT = 1; KS = 9; break;
        case 4: w = off_w1; pk = po1;  CIN = 32; NT = 1; KS = 9; break;
        case 5: w = off_w2; pk = po2;  CIN = 32; NT = 1; KS = 9; break;
        case 6: w = dcn_off_w; pk = pow_; CIN = 16; NT = 9; KS = 5; break;
        default: w = dcn_w; pk = pd;   CIN = 16; NT = 1; KS = 5; break;
    }
    if (i >= KS * NT * 512) return;
    int e = i & 7, lane = (i >> 3) & 63, rest = i >> 9;
    int nt = rest % NT, ks = rest / NT;
    int k = ks * 32 + (lane >> 4) * 8 + e;
    int n = nt * 16 + (lane & 15);
    int t, ci;
    if (CIN == 16) { t = k >> 4; ci = k & 15; } else { t = k >> 5; ci = k & 31; }
    float v = (t < 9) ? w[(n * CIN + ci) * 9 + t] : 0.f;
    pk[i] = f2bf(v);
}

// ---------------- FE conv (CIN=16) on MFMA; both images via z ---------------
// output: cat buffer [pix][32] bf16 at channel offset img*16
template <bool PLANAR>
__launch_bounds__(256)
__global__ void fe_mfma_k(const float* __restrict__ pA, const float* __restrict__ pB,
                          const ushort* __restrict__ catin,
                          const ushort* __restrict__ pack, const float* __restrict__ bias,
                          ushort* __restrict__ catout,
                          int H, int W, int OH, int OW, int pad) {
    __shared__ ushort patch[324 * 16];               // [pos(18x18)][ci]
    const int tid = threadIdx.x;
    const int tx0 = blockIdx.x * 16, ty0 = blockIdx.y * 16;
    const int b = blockIdx.z & 3, img = blockIdx.z >> 2;
    const int bx = tx0 - pad, by = ty0 - pad;
    const int HW = H * W;

    if (PLANAR) {
        const float* inb = (img ? pB : pA) + (size_t)(b * 16) * HW;
        for (int pos = tid; pos < 324; pos += 256) {
            int r = pos / 18, c = pos - r * 18;
            int gy = by + r, gx = bx + c;
            bool ok = (unsigned)gy < (unsigned)H && (unsigned)gx < (unsigned)W;
            int base = gy * W + gx;
            uint o16[8];
#pragma unroll
            for (int ii = 0; ii < 8; ++ii) {
                float lo = ok ? inb[(2 * ii) * HW + base] : 0.f;
                float hi = ok ? inb[(2 * ii + 1) * HW + base] : 0.f;
                o16[ii] = (uint)f2bf(lo) | ((uint)f2bf(hi) << 16);
            }
            *(uint4*)(patch + pos * 16) = *(uint4*)&o16[0];
            *(uint4*)(patch + pos * 16 + 8) = *(uint4*)&o16[4];
        }
    } else {
        for (int c = tid; c < 648; c += 256) {
            int pos = c >> 1, h = c & 1;
            int r = pos / 18, col = pos - r * 18;
            int gy = by + r, gx = bx + col;
            uint4 v = make_uint4(0, 0, 0, 0);
            if ((unsigned)gy < (unsigned)H && (unsigned)gx < (unsigned)W)
                v = *(const uint4*)(catin + ((size_t)(b * H + gy) * W + gx) * 32 + img * 16 + h * 8);
            *(uint4*)(patch + pos * 16 + h * 8) = v;
        }
    }
    __syncthreads();

    const int lane = tid & 63, wv = tid >> 6;
    const int g = lane >> 4, ci0 = (g & 1) * 8, rowx = lane & 15;
    f32x4 acc[4];
    float bv = bias[rowx];
#pragma unroll
    for (int m = 0; m < 4; ++m) acc[m] = f32x4{bv, bv, bv, bv};

#pragma unroll
    for (int ks = 0; ks < 5; ++ks) {
        int t = 2 * ks + (g >> 1);
        int dy = t < 9 ? t / 3 : 0;
        int dx = t < 9 ? t - (t / 3) * 3 : 0;
        bf16x8 a[4];
#pragma unroll
        for (int m = 0; m < 4; ++m) {
            int r = wv * 4 + m + dy, cc = rowx + dx;
            a[m] = *(const bf16x8*)(patch + (r * 18 + cc) * 16 + ci0);
        }
        bf16x8 bfrag = *(const bf16x8*)((const uint4*)pack + ks * 64 + lane);
#pragma unroll
        for (int m = 0; m < 4; ++m)
            acc[m] = __builtin_amdgcn_mfma_f32_16x16x32_bf16(a[m], bfrag, acc[m], 0, 0, 0);
    }

    const int oxb = g * 4;
#pragma unroll
    for (int m = 0; m < 4; ++m) {
        int gy = ty0 + wv * 4 + m;
        if (gy >= OH) continue;
#pragma unroll
        for (int j = 0; j < 4; ++j) {
            int gx = tx0 + oxb + j;
            if (gx < OW)
                catout[((size_t)(b * OH + gy) * OW + gx) * 32 + img * 16 + rowx] =
                    f2bf(fmaxf(acc[m][j], 0.f));
        }
    }
}

// ---------------- offset-feature conv (CIN=32) on MFMA, 3 scales ------------
__launch_bounds__(256)
__global__ void off_mfma_k(const ushort* __restrict__ c0, const ushort* __restrict__ c1,
                           const ushort* __restrict__ c2,
                           const ushort* __restrict__ pk0, const ushort* __restrict__ pk1,
                           const ushort* __restrict__ pk2,
                           const float* __restrict__ b0, const float* __restrict__ b1,
                           const float* __restrict__ b2,
                           ushort* __restrict__ f0, ushort* __restrict__ f1,
                           ushort* __restrict__ f2) {
    const int z = blockIdx.z, s = z >> 2, b = z & 3;
    const int H = 192 - 2 * s, W = H;
    const ushort* cat  = s == 0 ? c0 : (s == 1 ? c1 : c2);
    const ushort* pack = s == 0 ? pk0 : (s == 1 ? pk1 : pk2);
    const float* bias  = s == 0 ? b0 : (s == 1 ? b1 : b2);
    ushort* out        = s == 0 ? f0 : (s == 1 ? f1 : f2);

    __shared__ ushort patch[324 * 32];               // 20.7 KB
    const int tid = threadIdx.x;
    const int tx0 = blockIdx.x * 16, ty0 = blockIdx.y * 16;
    const int bx = tx0 - 1, by = ty0 - 1;

    for (int c = tid; c < 1296; c += 256) {
        int pos = c >> 2, h = c & 3;
        int r = pos / 18, col = pos - r * 18;
        int gy = by + r, gx = bx + col;
        uint4 v = make_uint4(0, 0, 0, 0);
        if ((unsigned)gy < (unsigned)H && (unsigned)gx < (unsigned)W)
            v = *(const uint4*)(cat + ((size_t)(b * H + gy) * W + gx) * 32 + h * 8);
        *(uint4*)(patch + pos * 32 + h * 8) = v;
    }
    __syncthreads();

    const int lane = tid & 63, wv = tid >> 6;
    const int g = lane >> 4, ci0 = g * 8, rowx = lane & 15;
    f32x4 acc[4];
    float bv = bias[rowx];
#pragma unroll
    for (int m = 0; m < 4; ++m) acc[m] = f32x4{bv, bv, bv, bv};

#pragma unroll
    for (int ks = 0; ks < 9; ++ks) {                 // K = 9 taps x 32ci exactly
        int dy = ks / 3, dx = ks - (ks / 3) * 3;
        bf16x8 a[4];
#pragma unroll
        for (int m = 0; m < 4; ++m) {
            int r = wv * 4 + m + dy, cc = rowx + dx;
            a[m] = *(const bf16x8*)(patch + (r * 18 + cc) * 32 + ci0);
        }
        bf16x8 bfrag = *(const bf16x8*)((const uint4*)pack + ks * 64 + lane);
#pragma unroll
        for (int m = 0; m < 4; ++m)
            acc[m] = __builtin_amdgcn_mfma_f32_16x16x32_bf16(a[m], bfrag, acc[m], 0, 0, 0);
    }

    const int oxb = g * 4;
#pragma unroll
    for (int m = 0; m < 4; ++m) {
        int gy = ty0 + wv * 4 + m;
        if (gy >= H) continue;
#pragma unroll
        for (int j = 0; j < 4; ++j) {
            int gx = tx0 + oxb + j;
            if (gx < W)
                out[((size_t)(b * H + gy) * W + gx) * 16 + rowx] = f2bf(fmaxf(acc[m][j], 0.f));
        }
    }
}

// ---- FUSED: offset conv (MFMA) -> LDS offsets -> bilinear sample -> MFMA ----
// Per-row interleave; ks loops at unroll-1 to keep VGPR pressure low
// (r10: full unroll -> 200 VGPR -> 2 waves/SIMD; r9: forced (256,3) -> spills).
// Phase-1 A-fragments read directly from global fb (L1/L2-resident).
// x tile staged in LDS as bf16 ch-pairs (r13: global sampling = 2.3x slower).
__launch_bounds__(256)
__global__ void dcn_fused_k(const ushort* __restrict__ c0, const ushort* __restrict__ c1,
                            const ushort* __restrict__ c2,
                            const ushort* __restrict__ fb0, const ushort* __restrict__ fb1,
                            const ushort* __restrict__ fb2,
                            const ushort* __restrict__ owPack, const float* __restrict__ ob,
                            const ushort* __restrict__ pd, const float* __restrict__ db,
                            float* __restrict__ o0, float* __restrict__ o1,
                            float* __restrict__ o2) {
    const int z = blockIdx.z;
    const int s = z >> 2, b = z & 3;
    const int H = 192 - 2 * s, W = H;
    const ushort* cat = s == 0 ? c0 : (s == 1 ? c1 : c2);
    const ushort* fb  = s == 0 ? fb0 : (s == 1 ? fb1 : fb2);
    float* out        = s == 0 ? o0 : (s == 1 ? o1 : o2);
    const int HW = H * W;
    const size_t pixb = (size_t)b * HW;

    __shared__ uint   xtu[8 * 484];      // x tile (bf16 ch-pairs), halo 3, 15488 B
    __shared__ ushort ot[4 * 16 * 152];  // per-wave offsets [16 px][152], 19456 B

    const int tid = threadIdx.x;
    const int tx0 = blockIdx.x * 16, ty0 = blockIdx.y * 16;

    // ---- stage x tile (halo 3, bf16 ch-pairs) ----
    {
        const int bx3 = tx0 - 3, by3 = ty0 - 3;
        for (int pos = tid; pos < 484; pos += 256) {
            int r = pos / 22, c = pos - r * 22;
            int gy2 = by3 + r, gx2 = bx3 + c;
            uint4 va = make_uint4(0, 0, 0, 0), vb = va;
            if ((unsigned)gy2 < (unsigned)H && (unsigned)gx2 < (unsigned)W) {
                const ushort* src = cat + (pixb + gy2 * W + gx2) * 32 + 16;
                va = *(const uint4*)src;
                vb = *(const uint4*)(src + 8);
            }
            xtu[0 * 484 + pos] = va.x; xtu[1 * 484 + pos] = va.y;
            xtu[2 * 484 + pos] = va.z; xtu[3 * 484 + pos] = va.w;
            xtu[4 * 484 + pos] = vb.x; xtu[5 * 484 + pos] = vb.y;
            xtu[6 * 484 + pos] = vb.z; xtu[7 * 484 + pos] = vb.w;
        }
    }
    __syncthreads();

    const int lane = tid & 63, wv = tid >> 6;
    const int g = lane >> 4, rowx = lane & 15, half = g & 1;
    const int ci0 = half * 8;
    const int px = tx0 + rowx;
    const float bv2 = db[rowx];
    ushort* otw = ot + wv * (16 * 152);

#pragma unroll 1
    for (int m = 0; m < 4; ++m) {
        const int py = ty0 + wv * 4 + m;

        // A-fragment loader for phase 1 (tap t may be 9 = pad; B is zero there)
        auto loadA = [&](int ks) -> uint4 {
            int t = 2 * ks + (g >> 1);
            int tc = t < 9 ? t : 0;
            int dy = tc / 3, dx = tc - (tc / 3) * 3;
            int gya = ty0 - 1 + wv * 4 + m + dy;
            int gxa = tx0 - 1 + rowx + dx;
            uint4 r = make_uint4(0, 0, 0, 0);
            if ((unsigned)gya < (unsigned)H && (unsigned)gxa < (unsigned)W)
                r = *(const uint4*)(fb + ((size_t)(b * H + gya) * W + gxa) * 16 + ci0);
            return r;
        };

        // ---- phase 1: offset conv for row m (acc[9] only), pipelined ----
        f32x4 acc[9];
#pragma unroll
        for (int n = 0; n < 9; ++n) {
            float bv = ob[n * 16 + rowx];
            acc[n] = f32x4{bv, bv, bv, bv};
        }
        uint4 avc = loadA(0);
#pragma unroll 1
        for (int ks = 0; ks < 5; ++ks) {
            uint4 avn = make_uint4(0, 0, 0, 0);
            if (ks < 4) avn = loadA(ks + 1);
            bf16x8 a = *(bf16x8*)&avc;
            const uint4* bp = (const uint4*)owPack + (size_t)(ks * 9) * 64 + lane;
#pragma unroll
            for (int n = 0; n < 9; ++n) {
                bf16x8 bfrag = *(const bf16x8*)(bp + (size_t)n * 64);
                acc[n] = __builtin_amdgcn_mfma_f32_16x16x32_bf16(a, bfrag, acc[n], 0, 0, 0);
            }
            avc = avn;
        }

        // ---- repack row m into wave-private LDS: [px][tap*16 + dg*2 + comp] ----
#pragma unroll
        for (int n = 0; n < 9; ++n) {
            int ch = n * 16 + rowx;              // 0..143
            int dg = ch / 18;
            int rem = ch - dg * 18;
            int col = (rem >> 1) * 16 + dg * 2 + (rem & 1);
#pragma unroll
            for (int j = 0; j < 4; ++j)
                otw[(g * 4 + j) * 152 + col] = f2bf(acc[n][j]);
        }

        // offsets loader for phase 2
        auto loadOV = [&](int ks) -> uint4 {
            int t = 2 * ks + (g >> 1);
            uint4 r = make_uint4(0, 0, 0, 0);
            if (t < 9) r = *(const uint4*)(otw + rowx * 152 + t * 16 + half * 8);
            return r;
        };

        // ---- phase 2: sample + deform-conv MFMA for row m, pipelined ----
        f32x4 acc2 = f32x4{bv2, bv2, bv2, bv2};
        uint4 ovc = loadOV(0);
#pragma unroll 1
        for (int ks = 0; ks < 5; ++ks) {
            uint4 ovn = make_uint4(0, 0, 0, 0);
            if (ks < 4) ovn = loadOV(ks + 1);
            const int t = 2 * ks + (g >> 1);
            const bool tv = (t < 9);
            const int t3 = t / 3;
            const int ky = (tv ? t3 : 0) - 1, kx = (tv ? t - t3 * 3 : 0) - 1;

            uint a2[4];
            if (tv) {
                uint ovv[4] = {ovc.x, ovc.y, ovc.z, ovc.w};
#pragma unroll
                for (int d = 0; d < 4; ++d) {
                    const int dgA = half * 4 + d;
                    uint u = ovv[d];
                    float sy = (float)(py + ky) + bflo(u);
                    float sx = (float)(px + kx) + bfhi(u);
                    float fy = floorf(sy), fx = floorf(sx);
                    int y0 = (int)fy, x0 = (int)fx;
                    float wy = sy - fy, wx = sx - fx;
                    float wy1 = 1.f - wy, wx1 = 1.f - wx;
                    float w00 = wy1 * wx1, w01 = wy1 * wx, w10 = wy * wx1, w11 = wy * wx;
                    int ly = y0 - (ty0 - 3), lx = x0 - (tx0 - 3);
                    float2 v00, v01, v10, v11;
                    if ((unsigned)ly <= 20u && (unsigned)lx <= 20u) {
                        const uint* tt = &xtu[dgA * 484 + ly * 22 + lx];
                        uint u00 = tt[0], u01 = tt[1], u10 = tt[22], u11 = tt[23];
                        v00 = make_float2(bflo(u00), bfhi(u00));
                        v01 = make_float2(bflo(u01), bfhi(u01));
                        v10 = make_float2(bflo(u10), bfhi(u10));
                        v11 = make_float2(bflo(u11), bfhi(u11));
                    } else {
                        v00 = v01 = v10 = v11 = make_float2(0.f, 0.f);
                        bool y0v = (unsigned)y0 < (unsigned)H;
                        bool y1v = (unsigned)(y0 + 1) < (unsigned)H;
                        bool x0v = (unsigned)x0 < (unsigned)W;
                        bool x1v = (unsigned)(x0 + 1) < (unsigned)W;
                        const ushort* cg = cat + ((size_t)pixb + (size_t)y0 * W + x0) * 32 + 16 + 2 * dgA;
                        if (y0v && x0v) { uint uu = *(const uint*)cg;                 v00 = make_float2(bflo(uu), bfhi(uu)); }
                        if (y0v && x1v) { uint uu = *(const uint*)(cg + 32);          v01 = make_float2(bflo(uu), bfhi(uu)); }
                        if (y1v && x0v) { uint uu = *(const uint*)(cg + 32 * W);      v10 = make_float2(bflo(uu), bfhi(uu)); }
                        if (y1v && x1v) { uint uu = *(const uint*)(cg + 32 * W + 32); v11 = make_float2(bflo(uu), bfhi(uu)); }
                    }
                    float s0 = w00 * v00.x + w01 * v01.x + w10 * v10.x + w11 * v11.x;
                    float s1 = w00 * v00.y + w01 * v01.y + w10 * v10.y + w11 * v11.y;
                    a2[d] = (uint)f2bf(s0) | ((uint)f2bf(s1) << 16);
                }
            } else {
                a2[0] = a2[1] = a2[2] = a2[3] = 0u;
            }
            uint4 av = make_uint4(a2[0], a2[1], a2[2], a2[3]);
            bf16x8 af = *(bf16x8*)&av;
            bf16x8 dfrag = *(const bf16x8*)((const uint4*)pd + ks * 64 + lane);
            acc2 = __builtin_amdgcn_mfma_f32_16x16x32_bf16(af, dfrag, acc2, 0, 0, 0);
            ovc = ovn;
        }

        // ---- store row m: out channel = rowx, image col = g*4+j ----
        if (py < H) {
            float* op = out + (size_t)(b * 16 + rowx) * HW + (size_t)py * W;
#pragma unroll
            for (int j = 0; j < 4; ++j) {
                int gx2 = tx0 + g * 4 + j;
                if (gx2 < W) op[gx2] = acc2[j];
            }
        }
    }
}

// ---------------------------------------------------------------------------
extern "C" void kernel_launch(void* const* d_in, const int* in_sizes, int n_in,
                              void* d_out, int out_size, void* d_ws, size_t ws_size,
                              hipStream_t stream) {
    const float* ref_image = (const float*)d_in[0];
    const float* unreg_image = (const float*)d_in[1];
    const float* fe_w1 = (const float*)d_in[2];
    const float* fe_b1 = (const float*)d_in[3];
    const float* fe_w2 = (const float*)d_in[4];
    const float* fe_b2 = (const float*)d_in[5];
    const float* fe_w3 = (const float*)d_in[6];
    const float* fe_b3 = (const float*)d_in[7];
    const float* off_w0 = (const float*)d_in[8];
    const float* off_b0 = (const float*)d_in[9];
    const float* off_w1 = (const float*)d_in[10];
    const float* off_b1 = (const float*)d_in[11];
    const float* off_w2 = (const float*)d_in[12];
    const float* off_b2 = (const float*)d_in[13];
    const float* dcn_off_w = (const float*)d_in[14];
    const float* dcn_off_b = (const float*)d_in[15];
    const float* dcn_w = (const float*)d_in[16];
    const float* dcn_b = (const float*)d_in[17];

    const size_t pix[3] = {4ul * 192 * 192, 4ul * 190 * 190, 4ul * 188 * 188};
    const size_t szf[3] = {pix[0] * 16, pix[1] * 16, pix[2] * 16};

    size_t o = 0;
    auto take = [&](size_t bytes) {
        void* r = (char*)d_ws + o;
        o += (bytes + 255) & ~(size_t)255;
        return r;
    };
    ushort* cat[3]; ushort* fb[3];
    ushort* pf[3]; ushort* po[3]; ushort* owPack; ushort* pd;
    for (int s = 0; s < 3; ++s) cat[s] = (ushort*)take(pix[s] * 32 * 2);
    for (int s = 0; s < 3; ++s) fb[s] = (ushort*)take(pix[s] * 16 * 2);
    for (int s = 0; s < 3; ++s) pf[s] = (ushort*)take(2560 * 2);
    for (int s = 0; s < 3; ++s) po[s] = (ushort*)take(4608 * 2);
    owPack = (ushort*)take(23040 * 2);
    pd = (ushort*)take(2560 * 2);

    float* out0 = (float*)d_out;
    float* out1 = out0 + szf[0];
    float* out2 = out1 + szf[1];

    dim3 blk(256);

    packall_k<<<dim3(90, 8), blk, 0, stream>>>(
        fe_w1, fe_w2, fe_w3, off_w0, off_w1, off_w2, dcn_off_w, dcn_w,
        pf[0], pf[1], pf[2], po[0], po[1], po[2], owPack, pd);

    // FE convs (both images per launch), output -> cat buffers
    fe_mfma_k<true><<<dim3(12, 12, 8), blk, 0, stream>>>(
        ref_image, unreg_image, nullptr, pf[0], fe_b1, cat[0], 192, 192, 192, 192, 1);
    fe_mfma_k<false><<<dim3(12, 12, 8), blk, 0, stream>>>(
        nullptr, nullptr, cat[0], pf[1], fe_b2, cat[1], 192, 192, 190, 190, 0);
    fe_mfma_k<false><<<dim3(12, 12, 8), blk, 0, stream>>>(
        nullptr, nullptr, cat[1], pf[2], fe_b3, cat[2], 190, 190, 188, 188, 0);

    // offset-feature convs (all scales)
    off_mfma_k<<<dim3(12, 12, 12), blk, 0, stream>>>(
        cat[0], cat[1], cat[2], po[0], po[1], po[2],
        off_b0, off_b1, off_b2, fb[0], fb[1], fb[2]);

    // fused dcn-offset conv + deformable conv (all scales)
    dcn_fused_k<<<dim3(12, 12, 12), blk, 0, stream>>>(
        cat[0], cat[1], cat[2], fb[0], fb[1], fb[2],
        owPack, dcn_off_b, pd, dcn_b, out0, out1, out2);
}

// Round 16
// 160.210 us; speedup vs baseline: 2.0676x; 1.0957x over previous
//
#include <hip/hip_runtime.h>

typedef unsigned int uint;
typedef unsigned short ushort;
typedef __attribute__((ext_vector_type(8))) short bf16x8;
typedef __attribute__((ext_vector_type(4))) float f32x4;

__device__ inline ushort f2bf(float f) {           // f32 -> bf16 RNE
    uint u = __float_as_uint(f);
    u += 0x7fff + ((u >> 16) & 1);
    return (ushort)(u >> 16);
}
__device__ inline uint pkbf(float lo, float hi) {  // 2xf32 -> packed bf16 pair (RNE)
    uint r;
    asm("v_cvt_pk_bf16_f32 %0, %1, %2" : "=v"(r) : "v"(lo), "v"(hi));
    return r;
}
__device__ inline float bflo(uint w) { return __uint_as_float(w << 16); }
__device__ inline float bfhi(uint w) { return __uint_as_float(w & 0xffff0000u); }

// ---- pack all weights into MFMA fragment order (bf16) ----------------------
// y 0..5: B-frags, generic: k = ks*32+(lane>>4)*8+e ; n = lane&15 ; t=k/CIN ci=k%CIN
// y == 6: dcn_off_w -> A-frags for SWAPPED offset conv (C^T = W·X):
//         M-row = lane&15 = ch-within-tile; output channel permuted so that
//         D-holder lane (g,rowx) gets (tap=n, dg=2g+(reg>>1), comp=reg&1).
// y == 7: dcn_w -> B-frags with phase-2 k-map:
//         tap = 2ks+(e>>2), dg = 2*(lane>>4)+((e>>1)&1), ci = dg*2+(e&1).
__global__ void packall_k(
    const float* __restrict__ fe_w1, const float* __restrict__ fe_w2,
    const float* __restrict__ fe_w3, const float* __restrict__ off_w0,
    const float* __restrict__ off_w1, const float* __restrict__ off_w2,
    const float* __restrict__ dcn_off_w, const float* __restrict__ dcn_w,
    ushort* __restrict__ pf1, ushort* __restrict__ pf2, ushort* __restrict__ pf3,
    ushort* __restrict__ po0, ushort* __restrict__ po1, ushort* __restrict__ po2,
    ushort* __restrict__ pow_, ushort* __restrict__ pd) {
    const int y = blockIdx.y;
    int i = blockIdx.x * 256 + threadIdx.x;
    int e = i & 7, lane = (i >> 3) & 63, rest = i >> 9;
    if (y == 6) {
        if (i >= 23040) return;
        int nt = rest % 9, ks = rest / 9;
        int m_idx = lane & 15;
        int ghat = m_idx >> 2, rhat = m_idx & 3;
        int c_orig = (2 * ghat + (rhat >> 1)) * 18 + nt * 2 + (rhat & 1);
        int k = ks * 32 + (lane >> 4) * 8 + e;
        int tapk = k >> 4, ci = k & 15;
        float v = (tapk < 9) ? dcn_off_w[(c_orig * 16 + ci) * 9 + tapk] : 0.f;
        pow_[i] = f2bf(v);
        return;
    }
    if (y == 7) {
        if (i >= 2560) return;
        int ks = rest;
        int co = lane & 15;
        int tap = 2 * ks + (e >> 2);
        int dg = 2 * (lane >> 4) + ((e >> 1) & 1);
        int ci = dg * 2 + (e & 1);
        float v = (tap < 9) ? dcn_w[(co * 16 + ci) * 9 + tap] : 0.f;
        pd[i] = f2bf(v);
        return;
    }
    const float* w; ushort* pk; int CIN, KS;
    switch (y) {
        case 0: w = fe_w1;  pk = pf1;  CIN = 16; KS = 5; break;
        case 1: w = fe_w2;  pk = pf2;  CIN = 16; KS = 5; break;
        case 2: w = fe_w3;  pk = pf3;  CIN = 16; KS = 5; break;
        case 3: w = off_w0; pk = po0;  CIN = 32; KS = 9; break;
        case 4: w = off_w1; pk = po1;  CIN = 32; KS = 9; break;
        default: w = off_w2; pk = po2; CIN = 32; KS = 9; break;
    }
    if (i >= KS * 512) return;
    int ks = rest;
    int k = ks * 32 + (lane >> 4) * 8 + e;
    int n = lane & 15;
    int t, ci;
    if (CIN == 16) { t = k >> 4; ci = k & 15; } else { t = k >> 5; ci = k & 31; }
    float v = (t < 9) ? w[(n * CIN + ci) * 9 + t] : 0.f;
    pk[i] = f2bf(v);
}

// ---------------- FE conv (CIN=16) on MFMA; both images via z ---------------
// output: cat buffer [pix][32] bf16 at channel offset img*16
template <bool PLANAR>
__launch_bounds__(256)
__global__ void fe_mfma_k(const float* __restrict__ pA, const float* __restrict__ pB,
                          const ushort* __restrict__ catin,
                          const ushort* __restrict__ pack, const float* __restrict__ bias,
                          ushort* __restrict__ catout,
                          int H, int W, int OH, int OW, int pad) {
    __shared__ ushort patch[324 * 16];               // [pos(18x18)][ci]
    const int tid = threadIdx.x;
    const int tx0 = blockIdx.x * 16, ty0 = blockIdx.y * 16;
    const int b = blockIdx.z & 3, img = blockIdx.z >> 2;
    const int bx = tx0 - pad, by = ty0 - pad;
    const int HW = H * W;

    if (PLANAR) {
        const float* inb = (img ? pB : pA) + (size_t)(b * 16) * HW;
        for (int pos = tid; pos < 324; pos += 256) {
            int r = pos / 18, c = pos - r * 18;
            int gy = by + r, gx = bx + c;
            bool ok = (unsigned)gy < (unsigned)H && (unsigned)gx < (unsigned)W;
            int base = gy * W + gx;
            uint o16[8];
#pragma unroll
            for (int ii = 0; ii < 8; ++ii) {
                float lo = ok ? inb[(2 * ii) * HW + base] : 0.f;
                float hi = ok ? inb[(2 * ii + 1) * HW + base] : 0.f;
                o16[ii] = (uint)f2bf(lo) | ((uint)f2bf(hi) << 16);
            }
            *(uint4*)(patch + pos * 16) = *(uint4*)&o16[0];
            *(uint4*)(patch + pos * 16 + 8) = *(uint4*)&o16[4];
        }
    } else {
        for (int c = tid; c < 648; c += 256) {
            int pos = c >> 1, h = c & 1;
            int r = pos / 18, col = pos - r * 18;
            int gy = by + r, gx = bx + col;
            uint4 v = make_uint4(0, 0, 0, 0);
            if ((unsigned)gy < (unsigned)H && (unsigned)gx < (unsigned)W)
                v = *(const uint4*)(catin + ((size_t)(b * H + gy) * W + gx) * 32 + img * 16 + h * 8);
            *(uint4*)(patch + pos * 16 + h * 8) = v;
        }
    }
    __syncthreads();

    const int lane = tid & 63, wv = tid >> 6;
    const int g = lane >> 4, ci0 = (g & 1) * 8, rowx = lane & 15;
    f32x4 acc[4];
    float bv = bias[rowx];
#pragma unroll
    for (int m = 0; m < 4; ++m) acc[m] = f32x4{bv, bv, bv, bv};

#pragma unroll
    for (int ks = 0; ks < 5; ++ks) {
        int t = 2 * ks + (g >> 1);
        int dy = t < 9 ? t / 3 : 0;
        int dx = t < 9 ? t - (t / 3) * 3 : 0;
        bf16x8 a[4];
#pragma unroll
        for (int m = 0; m < 4; ++m) {
            int r = wv * 4 + m + dy, cc = rowx + dx;
            a[m] = *(const bf16x8*)(patch + (r * 18 + cc) * 16 + ci0);
        }
        bf16x8 bfrag = *(const bf16x8*)((const uint4*)pack + ks * 64 + lane);
#pragma unroll
        for (int m = 0; m < 4; ++m)
            acc[m] = __builtin_amdgcn_mfma_f32_16x16x32_bf16(a[m], bfrag, acc[m], 0, 0, 0);
    }

    const int oxb = g * 4;
#pragma unroll
    for (int m = 0; m < 4; ++m) {
        int gy = ty0 + wv * 4 + m;
        if (gy >= OH) continue;
#pragma unroll
        for (int j = 0; j < 4; ++j) {
            int gx = tx0 + oxb + j;
            if (gx < OW)
                catout[((size_t)(b * OH + gy) * OW + gx) * 32 + img * 16 + rowx] =
                    f2bf(fmaxf(acc[m][j], 0.f));
        }
    }
}

// ---------------- offset-feature conv (CIN=32) on MFMA, 3 scales ------------
__launch_bounds__(256)
__global__ void off_mfma_k(const ushort* __restrict__ c0, const ushort* __restrict__ c1,
                           const ushort* __restrict__ c2,
                           const ushort* __restrict__ pk0, const ushort* __restrict__ pk1,
                           const ushort* __restrict__ pk2,
                           const float* __restrict__ b0, const float* __restrict__ b1,
                           const float* __restrict__ b2,
                           ushort* __restrict__ f0, ushort* __restrict__ f1,
                           ushort* __restrict__ f2) {
    const int z = blockIdx.z, s = z >> 2, b = z & 3;
    const int H = 192 - 2 * s, W = H;
    const ushort* cat  = s == 0 ? c0 : (s == 1 ? c1 : c2);
    const ushort* pack = s == 0 ? pk0 : (s == 1 ? pk1 : pk2);
    const float* bias  = s == 0 ? b0 : (s == 1 ? b1 : b2);
    ushort* out        = s == 0 ? f0 : (s == 1 ? f1 : f2);

    __shared__ ushort patch[324 * 32];               // 20.7 KB
    const int tid = threadIdx.x;
    const int tx0 = blockIdx.x * 16, ty0 = blockIdx.y * 16;
    const int bx = tx0 - 1, by = ty0 - 1;

    for (int c = tid; c < 1296; c += 256) {
        int pos = c >> 2, h = c & 3;
        int r = pos / 18, col = pos - r * 18;
        int gy = by + r, gx = bx + col;
        uint4 v = make_uint4(0, 0, 0, 0);
        if ((unsigned)gy < (unsigned)H && (unsigned)gx < (unsigned)W)
            v = *(const uint4*)(cat + ((size_t)(b * H + gy) * W + gx) * 32 + h * 8);
        *(uint4*)(patch + pos * 32 + h * 8) = v;
    }
    __syncthreads();

    const int lane = tid & 63, wv = tid >> 6;
    const int g = lane >> 4, ci0 = g * 8, rowx = lane & 15;
    f32x4 acc[4];
    float bv = bias[rowx];
#pragma unroll
    for (int m = 0; m < 4; ++m) acc[m] = f32x4{bv, bv, bv, bv};

#pragma unroll
    for (int ks = 0; ks < 9; ++ks) {                 // K = 9 taps x 32ci exactly
        int dy = ks / 3, dx = ks - (ks / 3) * 3;
        bf16x8 a[4];
#pragma unroll
        for (int m = 0; m < 4; ++m) {
            int r = wv * 4 + m + dy, cc = rowx + dx;
            a[m] = *(const bf16x8*)(patch + (r * 18 + cc) * 32 + ci0);
        }
        bf16x8 bfrag = *(const bf16x8*)((const uint4*)pack + ks * 64 + lane);
#pragma unroll
        for (int m = 0; m < 4; ++m)
            acc[m] = __builtin_amdgcn_mfma_f32_16x16x32_bf16(a[m], bfrag, acc[m], 0, 0, 0);
    }

    const int oxb = g * 4;
#pragma unroll
    for (int m = 0; m < 4; ++m) {
        int gy = ty0 + wv * 4 + m;
        if (gy >= H) continue;
#pragma unroll
        for (int j = 0; j < 4; ++j) {
            int gx = tx0 + oxb + j;
            if (gx < W)
                out[((size_t)(b * H + gy) * W + gx) * 16 + rowx] = f2bf(fmaxf(acc[m][j], 0.f));
        }
    }
}

// ---- FUSED: swapped offset conv (C^T, offsets land lane-local) -> sample ---
// Phase 1 computes D[ch][pix] = W·X so lane (g,rowx) holds, for ITS pixel
// rowx, offsets (tap=n, dg=2g+(reg>>1), comp=reg&1) in acc[n][reg]. Phase 2's
// k-order (baked into pd) assigns lane the samples (tap=2ks+(u>>1),
// dg=2g+(u&1)) -> all offsets are statically-indexed registers. No LDS
// repack, no ot buffer, offsets stay f32.
__launch_bounds__(256)
__global__ void dcn_fused_k(const ushort* __restrict__ c0, const ushort* __restrict__ c1,
                            const ushort* __restrict__ c2,
                            const ushort* __restrict__ fb0, const ushort* __restrict__ fb1,
                            const ushort* __restrict__ fb2,
                            const ushort* __restrict__ owPack, const float* __restrict__ ob,
                            const ushort* __restrict__ pd, const float* __restrict__ db,
                            float* __restrict__ o0, float* __restrict__ o1,
                            float* __restrict__ o2) {
    const int z = blockIdx.z;
    const int s = z >> 2, b = z & 3;
    const int H = 192 - 2 * s, W = H;
    const ushort* cat = s == 0 ? c0 : (s == 1 ? c1 : c2);
    const ushort* fb  = s == 0 ? fb0 : (s == 1 ? fb1 : fb2);
    float* out        = s == 0 ? o0 : (s == 1 ? o1 : o2);
    const int HW = H * W;
    const size_t pixb = (size_t)b * HW;

    __shared__ uint xtu[8 * 484];        // x tile (bf16 ch-pairs), halo 3, 15488 B

    const int tid = threadIdx.x;
    const int tx0 = blockIdx.x * 16, ty0 = blockIdx.y * 16;

    // ---- stage x tile (halo 3, bf16 ch-pairs) ----
    {
        const int bx3 = tx0 - 3, by3 = ty0 - 3;
        for (int pos = tid; pos < 484; pos += 256) {
            int r = pos / 22, c = pos - r * 22;
            int gy2 = by3 + r, gx2 = bx3 + c;
            uint4 va = make_uint4(0, 0, 0, 0), vb = va;
            if ((unsigned)gy2 < (unsigned)H && (unsigned)gx2 < (unsigned)W) {
                const ushort* src = cat + (pixb + gy2 * W + gx2) * 32 + 16;
                va = *(const uint4*)src;
                vb = *(const uint4*)(src + 8);
            }
            xtu[0 * 484 + pos] = va.x; xtu[1 * 484 + pos] = va.y;
            xtu[2 * 484 + pos] = va.z; xtu[3 * 484 + pos] = va.w;
            xtu[4 * 484 + pos] = vb.x; xtu[5 * 484 + pos] = vb.y;
            xtu[6 * 484 + pos] = vb.z; xtu[7 * 484 + pos] = vb.w;
        }
    }
    __syncthreads();

    const int lane = tid & 63, wv = tid >> 6;
    const int g = lane >> 4, rowx = lane & 15;
    const int ci0 = (g & 1) * 8;
    const int px = tx0 + rowx;
    const float bv2 = db[rowx];

#pragma unroll 1
    for (int m = 0; m < 4; ++m) {
        const int py = ty0 + wv * 4 + m;

        // B-fragment loader (patch): k = ks*32 + g*8 + e -> tap 2ks+(g>>1), ci-half
        auto loadB = [&](int ks) -> uint4 {
            int t = 2 * ks + (g >> 1);
            int tc = t < 9 ? t : 0;
            int dy = tc / 3, dx = tc - (tc / 3) * 3;
            int gya = ty0 - 1 + wv * 4 + m + dy;
            int gxa = tx0 - 1 + rowx + dx;
            uint4 r = make_uint4(0, 0, 0, 0);
            if ((unsigned)gya < (unsigned)H && (unsigned)gxa < (unsigned)W)
                r = *(const uint4*)(fb + ((size_t)(b * H + gya) * W + gxa) * 16 + ci0);
            return r;
        };

        // ---- phase 1 (swapped): acc[n][r] = offset (tap=n, dg=2g+(r>>1), comp=r&1)
        f32x4 acc[9];
#pragma unroll
        for (int n = 0; n < 9; ++n) {
            f32x4 t;
#pragma unroll
            for (int r = 0; r < 4; ++r)
                t[r] = ob[(2 * g + (r >> 1)) * 18 + n * 2 + (r & 1)];
            acc[n] = t;
        }
        uint4 bvc = loadB(0);
#pragma unroll 1
        for (int ks = 0; ks < 5; ++ks) {
            uint4 bvn = make_uint4(0, 0, 0, 0);
            if (ks < 4) bvn = loadB(ks + 1);
            bf16x8 bfrag = *(bf16x8*)&bvc;
            const uint4* ap = (const uint4*)owPack + (size_t)(ks * 9) * 64 + lane;
#pragma unroll
            for (int n = 0; n < 9; ++n) {
                bf16x8 afrag = *(const bf16x8*)(ap + (size_t)n * 64);
                acc[n] = __builtin_amdgcn_mfma_f32_16x16x32_bf16(afrag, bfrag, acc[n], 0, 0, 0);
            }
            bvc = bvn;
        }

        // ---- phase 2: sample + deform-conv MFMA (ks fully unrolled; offsets
        //      are statically-indexed registers) ----
        f32x4 acc2 = f32x4{bv2, bv2, bv2, bv2};
#pragma unroll
        for (int ks = 0; ks < 5; ++ks) {
            uint a2[4];
#pragma unroll
            for (int u = 0; u < 4; ++u) {
                const int tap = 2 * ks + (u >> 1);
                if (tap < 9) {
                    const int dgA = 2 * g + (u & 1);
                    const int ky = tap / 3 - 1, kx = tap % 3 - 1;
                    float sy = (float)(py + ky) + acc[tap][(u & 1) * 2];
                    float sx = (float)(px + kx) + acc[tap][(u & 1) * 2 + 1];
                    float fy = floorf(sy), fx = floorf(sx);
                    int y0 = (int)fy, x0 = (int)fx;
                    float wy = sy - fy, wx = sx - fx;
                    float wy1 = 1.f - wy, wx1 = 1.f - wx;
                    float w00 = wy1 * wx1, w01 = wy1 * wx, w10 = wy * wx1, w11 = wy * wx;
                    int ly = y0 - (ty0 - 3), lx = x0 - (tx0 - 3);
                    float2 v00, v01, v10, v11;
                    if ((unsigned)ly <= 20u && (unsigned)lx <= 20u) {
                        const uint* tt = &xtu[dgA * 484 + ly * 22 + lx];
                        uint u00 = tt[0], u01 = tt[1], u10 = tt[22], u11 = tt[23];
                        v00 = make_float2(bflo(u00), bfhi(u00));
                        v01 = make_float2(bflo(u01), bfhi(u01));
                        v10 = make_float2(bflo(u10), bfhi(u10));
                        v11 = make_float2(bflo(u11), bfhi(u11));
                    } else {
                        v00 = v01 = v10 = v11 = make_float2(0.f, 0.f);
                        bool y0v = (unsigned)y0 < (unsigned)H;
                        bool y1v = (unsigned)(y0 + 1) < (unsigned)H;
                        bool x0v = (unsigned)x0 < (unsigned)W;
                        bool x1v = (unsigned)(x0 + 1) < (unsigned)W;
                        const ushort* cg = cat + (pixb + (size_t)y0 * W + x0) * 32 + 16 + 2 * dgA;
                        if (y0v && x0v) { uint uu = *(const uint*)cg;                 v00 = make_float2(bflo(uu), bfhi(uu)); }
                        if (y0v && x1v) { uint uu = *(const uint*)(cg + 32);          v01 = make_float2(bflo(uu), bfhi(uu)); }
                        if (y1v && x0v) { uint uu = *(const uint*)(cg + 32 * W);      v10 = make_float2(bflo(uu), bfhi(uu)); }
                        if (y1v && x1v) { uint uu = *(const uint*)(cg + 32 * W + 32); v11 = make_float2(bflo(uu), bfhi(uu)); }
                    }
                    float s0 = w00 * v00.x + w01 * v01.x + w10 * v10.x + w11 * v11.x;
                    float s1 = w00 * v00.y + w01 * v01.y + w10 * v10.y + w11 * v11.y;
                    a2[u] = pkbf(s0, s1);
                } else {
                    a2[u] = 0u;
                }
            }
            uint4 av = make_uint4(a2[0], a2[1], a2[2], a2[3]);
            bf16x8 af = *(bf16x8*)&av;
            bf16x8 dfrag = *(const bf16x8*)((const uint4*)pd + ks * 64 + lane);
            acc2 = __builtin_amdgcn_mfma_f32_16x16x32_bf16(af, dfrag, acc2, 0, 0, 0);
        }

        // ---- store row m: out channel = rowx, image col = g*4+j ----
        if (py < H) {
            float* op = out + (size_t)(b * 16 + rowx) * HW + (size_t)py * W;
#pragma unroll
            for (int j = 0; j < 4; ++j) {
                int gx2 = tx0 + g * 4 + j;
                if (gx2 < W) op[gx2] = acc2[j];
            }
        }
    }
}

// ---------------------------------------------------------------------------
extern "C" void kernel_launch(void* const* d_in, const int* in_sizes, int n_in,
                              void* d_out, int out_size, void* d_ws, size_t ws_size,
                              hipStream_t stream) {
    const float* ref_image = (const float*)d_in[0];
    const float* unreg_image = (const float*)d_in[1];
    const float* fe_w1 = (const float*)d_in[2];
    const float* fe_b1 = (const float*)d_in[3];
    const float* fe_w2 = (const float*)d_in[4];
    const float* fe_b2 = (const float*)d_in[5];
    const float* fe_w3 = (const float*)d_in[6];
    const float* fe_b3 = (const float*)d_in[7];
    const float* off_w0 = (const float*)d_in[8];
    const float* off_b0 = (const float*)d_in[9];
    const float* off_w1 = (const float*)d_in[10];
    const float* off_b1 = (const float*)d_in[11];
    const float* off_w2 = (const float*)d_in[12];
    const float* off_b2 = (const float*)d_in[13];
    const float* dcn_off_w = (const float*)d_in[14];
    const float* dcn_off_b = (const float*)d_in[15];
    const float* dcn_w = (const float*)d_in[16];
    const float* dcn_b = (const float*)d_in[17];

    const size_t pix[3] = {4ul * 192 * 192, 4ul * 190 * 190, 4ul * 188 * 188};
    const size_t szf[3] = {pix[0] * 16, pix[1] * 16, pix[2] * 16};

    size_t o = 0;
    auto take = [&](size_t bytes) {
        void* r = (char*)d_ws + o;
        o += (bytes + 255) & ~(size_t)255;
        return r;
    };
    ushort* cat[3]; ushort* fb[3];
    ushort* pf[3]; ushort* po[3]; ushort* owPack; ushort* pd;
    for (int s = 0; s < 3; ++s) cat[s] = (ushort*)take(pix[s] * 32 * 2);
    for (int s = 0; s < 3; ++s) fb[s] = (ushort*)take(pix[s] * 16 * 2);
    for (int s = 0; s < 3; ++s) pf[s] = (ushort*)take(2560 * 2);
    for (int s = 0; s < 3; ++s) po[s] = (ushort*)take(4608 * 2);
    owPack = (ushort*)take(23040 * 2);
    pd = (ushort*)take(2560 * 2);

    float* out0 = (float*)d_out;
    float* out1 = out0 + szf[0];
    float* out2 = out1 + szf[1];

    dim3 blk(256);

    packall_k<<<dim3(90, 8), blk, 0, stream>>>(
        fe_w1, fe_w2, fe_w3, off_w0, off_w1, off_w2, dcn_off_w, dcn_w,
        pf[0], pf[1], pf[2], po[0], po[1], po[2], owPack, pd);

    // FE convs (both images per launch), output -> cat buffers
    fe_mfma_k<true><<<dim3(12, 12, 8), blk, 0, stream>>>(
        ref_image, unreg_image, nullptr, pf[0], fe_b1, cat[0], 192, 192, 192, 192, 1);
    fe_mfma_k<false><<<dim3(12, 12, 8), blk, 0, stream>>>(
        nullptr, nullptr, cat[0], pf[1], fe_b2, cat[1], 192, 192, 190, 190, 0);
    fe_mfma_k<false><<<dim3(12, 12, 8), blk, 0, stream>>>(
        nullptr, nullptr, cat[1], pf[2], fe_b3, cat[2], 190, 190, 188, 188, 0);

    // offset-feature convs (all scales)
    off_mfma_k<<<dim3(12, 12, 12), blk, 0, stream>>>(
        cat[0], cat[1], cat[2], po[0], po[1], po[2],
        off_b0, off_b1, off_b2, fb[0], fb[1], fb[2]);

    // fused dcn-offset conv + deformable conv (all scales)
    dcn_fused_k<<<dim3(12, 12, 12), blk, 0, stream>>>(
        cat[0], cat[1], cat[2], fb[0], fb[1], fb[2],
        owPack, dcn_off_b, pd, dcn_b, out0, out1, out2);
}